// Round 2
// baseline (215.418 us; speedup 1.0000x reference)
//
#include <hip/hip_runtime.h>
#include <math.h>

// Problem constants
#define BB    16
#define TT    2048
#define VOCAB 14
#define TOKD  8
#define POSD  8
#define DM    16      // TOKD + POSD
#define NH    2
#define HD    3
#define AD    6       // NH*HD
#define FFND  3

#define NTOK  (BB*TT)            // 32768
#define QPW   16                 // queries per wave
#define SUBL  4                  // key sub-lanes per query
#define WPBH  (TT/QPW)           // 128 waves per (b,h)
#define NWAVE (BB*NH*WPBH)       // 4096 waves

// ---------------------------------------------------------------------------
// Kernel 1: per-token prep. Gather+concat -> store pre-LN x; LN1; Q/K/V
// matvecs; store Q (prescaled by log2e/sqrt(3)) head-major, KV packed 32B.
// ---------------------------------------------------------------------------
__global__ __launch_bounds__(256) void prep_kernel(
    const int* __restrict__ idx,
    const float* __restrict__ tok_emb,
    const float* __restrict__ pos_enc,
    const float* __restrict__ Wq,
    const float* __restrict__ Wk,
    const float* __restrict__ Wv,
    const float* __restrict__ ln1w,
    const float* __restrict__ ln1b,
    float* __restrict__ xbuf,
    float* __restrict__ qbuf,
    float* __restrict__ kvbuf)
{
    int gid = blockIdx.x * blockDim.x + threadIdx.x;
    if (gid >= NTOK) return;
    int t = gid & (TT - 1);
    int b = gid >> 11;

    float x[DM];
    int tok = idx[gid];
    #pragma unroll
    for (int j = 0; j < TOKD; ++j) x[j]        = tok_emb[tok * TOKD + j];
    #pragma unroll
    for (int j = 0; j < POSD; ++j) x[TOKD + j] = pos_enc[t * POSD + j];

    // store pre-LN x (residual stream input)
    float* xp = xbuf + (size_t)gid * DM;
    #pragma unroll
    for (int j = 0; j < DM; j += 4)
        *(float4*)(xp + j) = make_float4(x[j], x[j+1], x[j+2], x[j+3]);

    // LN1
    float m = 0.f;
    #pragma unroll
    for (int j = 0; j < DM; ++j) m += x[j];
    m *= (1.f / DM);
    float v = 0.f;
    #pragma unroll
    for (int j = 0; j < DM; ++j) { float d = x[j] - m; v += d * d; }
    v *= (1.f / DM);
    float rs = rsqrtf(v + 1e-5f);
    float h[DM];
    #pragma unroll
    for (int j = 0; j < DM; ++j)
        h[j] = (x[j] - m) * rs * ln1w[j] + ln1b[j];

    // q,k from h[8..15] (pos part), v from h[0..7] (tok part)
    float q[AD], k[AD], vv[AD];
    #pragma unroll
    for (int a = 0; a < AD; ++a) {
        float sq = 0.f, sk = 0.f, sv = 0.f;
        #pragma unroll
        for (int j = 0; j < 8; ++j) {
            sq = fmaf(Wq[a * 8 + j], h[TOKD + j], sq);
            sk = fmaf(Wk[a * 8 + j], h[TOKD + j], sk);
            sv = fmaf(Wv[a * 8 + j], h[j], sv);
        }
        q[a] = sq; k[a] = sk; vv[a] = sv;
    }

    const float QS = 1.4426950408889634f / 1.7320508075688772f; // log2(e)/sqrt(HD)
    #pragma unroll
    for (int hh = 0; hh < NH; ++hh) {
        size_t base = (size_t)(b * NH + hh) * TT + t;
        *(float4*)(qbuf + base * 4) =
            make_float4(q[hh*3] * QS, q[hh*3+1] * QS, q[hh*3+2] * QS, 0.f);
        *(float4*)(kvbuf + base * 8) =
            make_float4(k[hh*3], k[hh*3+1], k[hh*3+2], 0.f);
        *(float4*)(kvbuf + base * 8 + 4) =
            make_float4(vv[hh*3], vv[hh*3+1], vv[hh*3+2], 0.f);
    }
}

// ---------------------------------------------------------------------------
// Kernel 2: causal attention. One wave = 16 consecutive query rows x 4 key
// sublanes. Keys stream sequentially (each KV read once per 16 queries).
// No max-subtraction (scores O(1)); combine sublanes with 2 shfl_xors.
// Heavy blocks (large i0) scheduled first.
// ---------------------------------------------------------------------------
__global__ __launch_bounds__(256) void attn_kernel(
    const float* __restrict__ qbuf,
    const float* __restrict__ kvbuf,
    float* __restrict__ abuf)
{
    int wglobal = blockIdx.x * 4 + (threadIdx.x >> 6);
    int w = (NWAVE - 1) - wglobal;          // heavy-first
    int bh  = w >> 7;                        // / WPBH
    int blk = w & (WPBH - 1);
    int i0  = blk << 4;                      // * QPW
    int lane = threadIdx.x & 63;
    int qi  = lane >> 2;                     // 0..15
    int sub = lane & 3;                      // 0..3
    int iq  = i0 + qi;                       // this lane's query row

    const float4 qv = *(const float4*)(qbuf + ((size_t)bh * TT + iq) * 4);
    const float q0 = qv.x, q1 = qv.y, q2 = qv.z;

    float l = 0.f, a0 = 0.f, a1 = 0.f, a2 = 0.f;
    const int nk = i0 + QPW;                 // wave needs keys 0..i0+15
    const float* kvb = kvbuf + (size_t)bh * TT * 8;

    #pragma unroll 4
    for (int t = sub; t < nk; t += SUBL) {
        float4 kk = *(const float4*)(kvb + (size_t)t * 8);
        float4 vz = *(const float4*)(kvb + (size_t)t * 8 + 4);
        float s = fmaf(q0, kk.x, fmaf(q1, kk.y, q2 * kk.z));
        float p = exp2f(s);
        p = (t <= iq) ? p : 0.f;
        l  += p;
        a0 = fmaf(p, vz.x, a0);
        a1 = fmaf(p, vz.y, a1);
        a2 = fmaf(p, vz.z, a2);
    }

    // combine the 4 sublanes (partial sums add directly: no max shift)
    #pragma unroll
    for (int mlane = 1; mlane <= 2; mlane <<= 1) {
        l  += __shfl_xor(l,  mlane);
        a0 += __shfl_xor(a0, mlane);
        a1 += __shfl_xor(a1, mlane);
        a2 += __shfl_xor(a2, mlane);
    }

    if (sub == 0) {
        int b = bh >> 1, head = bh & 1;
        float inv = 1.f / l;
        float* op = abuf + ((size_t)b * TT + iq) * AD + head * HD;
        op[0] = a0 * inv; op[1] = a1 * inv; op[2] = a2 * inv;
    }
}

// ---------------------------------------------------------------------------
// Kernel 3: per-token epilogue. Wo+residual, LN2, exact GELU FFN, residual,
// LNf, logits (16->8->14), f32 store.
// ---------------------------------------------------------------------------
__device__ __forceinline__ void layernorm16(
    const float* in, float* out, const float* w, const float* bsh)
{
    float m = 0.f;
    #pragma unroll
    for (int j = 0; j < DM; ++j) m += in[j];
    m *= (1.f / DM);
    float v = 0.f;
    #pragma unroll
    for (int j = 0; j < DM; ++j) { float d = in[j] - m; v += d * d; }
    v *= (1.f / DM);
    float rs = rsqrtf(v + 1e-5f);
    #pragma unroll
    for (int j = 0; j < DM; ++j)
        out[j] = (in[j] - m) * rs * w[j] + bsh[j];
}

__global__ __launch_bounds__(256) void epi_kernel(
    const float* __restrict__ xbuf,
    const float* __restrict__ abuf,
    const float* __restrict__ Wo,
    const float* __restrict__ ln2w,
    const float* __restrict__ ln2b,
    const float* __restrict__ lnfw,
    const float* __restrict__ lnfb,
    const float* __restrict__ W1,
    const float* __restrict__ b1,
    const float* __restrict__ W2,
    const float* __restrict__ b2,
    const float* __restrict__ Wh,
    const float* __restrict__ tok_emb,
    float* __restrict__ out)
{
    int gid = blockIdx.x * blockDim.x + threadIdx.x;
    if (gid >= NTOK) return;

    float x[DM];
    const float* xp = xbuf + (size_t)gid * DM;
    #pragma unroll
    for (int j = 0; j < DM; ++j) x[j] = xp[j];
    float att[AD];
    const float* ap = abuf + (size_t)gid * AD;
    #pragma unroll
    for (int a = 0; a < AD; ++a) att[a] = ap[a];

    // x += att @ Wo.T
    float xo[DM];
    #pragma unroll
    for (int j = 0; j < DM; ++j) {
        float s = x[j];
        #pragma unroll
        for (int a = 0; a < AD; ++a) s = fmaf(Wo[j * AD + a], att[a], s);
        xo[j] = s;
    }

    // LN2 -> FFN (exact gelu) -> residual
    float h2[DM];
    layernorm16(xo, h2, ln2w, ln2b);
    float g[FFND];
    #pragma unroll
    for (int c = 0; c < FFND; ++c) {
        float f = b1[c];
        #pragma unroll
        for (int j = 0; j < DM; ++j) f = fmaf(W1[c * DM + j], h2[j], f);
        g[c] = 0.5f * f * (1.f + erff(f * 0.70710678118654752f));
    }
    float x2[DM];
    #pragma unroll
    for (int j = 0; j < DM; ++j) {
        float s = xo[j] + b2[j];
        #pragma unroll
        for (int c = 0; c < FFND; ++c) s = fmaf(W2[j * FFND + c], g[c], s);
        x2[j] = s;
    }

    // LNf -> logits
    float y[DM];
    layernorm16(x2, y, lnfw, lnfb);
    float t8[TOKD];
    #pragma unroll
    for (int p = 0; p < TOKD; ++p) {
        float s = 0.f;
        #pragma unroll
        for (int j = 0; j < DM; ++j) s = fmaf(Wh[p * DM + j], y[j], s);
        t8[p] = s;
    }
    float* op = out + (size_t)gid * VOCAB;
    #pragma unroll
    for (int vcb = 0; vcb < VOCAB; ++vcb) {
        float s = 0.f;
        #pragma unroll
        for (int p = 0; p < TOKD; ++p) s = fmaf(t8[p], tok_emb[vcb * TOKD + p], s);
        op[vcb] = s;
    }
}

// ---------------------------------------------------------------------------
extern "C" void kernel_launch(void* const* d_in, const int* in_sizes, int n_in,
                              void* d_out, int out_size, void* d_ws, size_t ws_size,
                              hipStream_t stream) {
    const int*   idx     = (const int*)d_in[0];
    const float* tok_emb = (const float*)d_in[1];
    const float* pos_enc = (const float*)d_in[2];
    const float* Wq      = (const float*)d_in[3];
    const float* Wk      = (const float*)d_in[4];
    const float* Wv      = (const float*)d_in[5];
    const float* Wo      = (const float*)d_in[6];
    const float* ln1w    = (const float*)d_in[7];
    const float* ln1b    = (const float*)d_in[8];
    const float* ln2w    = (const float*)d_in[9];
    const float* ln2b    = (const float*)d_in[10];
    const float* lnfw    = (const float*)d_in[11];
    const float* lnfb    = (const float*)d_in[12];
    const float* W1      = (const float*)d_in[13];
    const float* b1      = (const float*)d_in[14];
    const float* W2      = (const float*)d_in[15];
    const float* b2      = (const float*)d_in[16];
    const float* Wh      = (const float*)d_in[17];
    float* out = (float*)d_out;

    float* xbuf  = (float*)d_ws;                         // NTOK*16 = 524288 f
    float* qbuf  = xbuf  + (size_t)NTOK * DM;            // B*NH*T*4 = 262144 f
    float* kvbuf = qbuf  + (size_t)BB * NH * TT * 4;     // B*NH*T*8 = 524288 f
    float* abuf  = kvbuf + (size_t)BB * NH * TT * 8;     // NTOK*6   = 196608 f

    prep_kernel<<<NTOK / 256, 256, 0, stream>>>(
        idx, tok_emb, pos_enc, Wq, Wk, Wv, ln1w, ln1b, xbuf, qbuf, kvbuf);

    attn_kernel<<<NWAVE / 4, 256, 0, stream>>>(qbuf, kvbuf, abuf);

    epi_kernel<<<NTOK / 256, 256, 0, stream>>>(
        xbuf, abuf, Wo, ln2w, ln2b, lnfw, lnfb, W1, b1, W2, b2, Wh, tok_emb, out);
}